// Round 5
// baseline (173.213 us; speedup 1.0000x reference)
//
#include <hip/hip_runtime.h>

// mean(|box5(x) - box5(y)|), box5 = 5x5 uniform, pad=4.
// box(x)-box(y) = box(x-y), separable.
//
// One WAVE owns a 512-wide strip of R=8 output rows; lane owns 8 cols.
// Vertical 5-row rolling sum in registers (ring[5][8]); horizontal 5-tap
// via 4 x __shfl_up. No LDS, no barriers.
//
// Round-5 change: EXPLICIT depth-4 software pipeline for the row loads.
// Evidence: compiler never hoists loads across row iterations on its own
// (VGPR stayed 44, BW pinned at 1.5 TB/s, duration invariant 66-74 us
// across 4 structural variants => per-wave MLP ~1 is the bottleneck).
// Stage registers sxa/sxc/sya/syc[4] hold raw float4 loads for rows
// k..k+3; step k consumes stage k%4 and re-issues it for row k+4.
// All indices compile-time after full unroll (no scratch). 16 loads in
// flight per wave instead of ~4.

#define IMG_W 512
#define IMG_H 512
#define OUT_W 516
#define OUT_H 516
#define R     8                  // output rows per wave strip
#define SPI   65                 // ceil(516/8)
#define NT    256
#define WAVES (NT / 64)
#define NSTRIPS (64 * SPI)       // 4160 waves
#define NBLK  (NSTRIPS / WAVES)  // 1040 blocks (130 per XCD)
#define NPART 64
#define DEPTH 4                  // pipeline stages (rows in flight)

__global__ __launch_bounds__(NT, 3) void box_loss_kernel(
    const float* __restrict__ x, const float* __restrict__ y,
    float* __restrict__ partial)
{
    const int t    = threadIdx.x;
    const int lane = t & 63;
    const int wid  = t >> 6;

    // bijective XCD swizzle: 1040 blocks -> 130 contiguous per XCD
    const int bid  = blockIdx.x;
    const int swz  = (bid & 7) * (NBLK / 8) + (bid >> 3);

    const int strip = swz * WAVES + wid;            // 0..4159
    const int b  = strip / SPI;                     // batch image
    const int s  = strip - b * SPI;                 // strip in image
    const int i0 = s * R;                           // first output row
    const int c0 = lane * 8;                        // this lane's 8 columns

    const float* xb = x + (size_t)b * (IMG_W * IMG_H) + c0;
    const float* yb = y + (size_t)b * (IMG_W * IMG_H) + c0;

    // pipeline stage registers: raw loads for DEPTH rows in flight
    float4 sxa[DEPTH], sxc[DEPTH], sya[DEPTH], syc[DEPTH];

    // issue loads for input row r into stage p (addresses clamped;
    // out-of-range rows masked at consume time)
    auto issue = [&](int p, int r) {
        const int rc = min(max(r, 0), IMG_H - 1);
        const float* xr = xb + (size_t)rc * IMG_W;
        const float* yr = yb + (size_t)rc * IMG_W;
        sxa[p] = *(const float4*)(xr);
        sxc[p] = *(const float4*)(xr + 4);
        sya[p] = *(const float4*)(yr);
        syc[p] = *(const float4*)(yr + 4);
    };

    // prologue: rows i0-4 .. i0-1 into stages 0..3
    #pragma unroll
    for (int p = 0; p < DEPTH; ++p) issue(p, i0 - 4 + p);

    // d-row history ring + vertical rolling sums, all in registers.
    float ring[5][8];
    float v[8];
    #pragma unroll
    for (int j = 0; j < 8; ++j) { v[j] = 0.f; ring[4][j] = 0.f; }

    float acc = 0.f;

    // 12 input rows: k=0..3 warm-up, k=4..11 produce output rows i0..i0+7
    #pragma unroll
    for (int k = 0; k < R + 4; ++k) {
        const int r = i0 - 4 + k;           // input row this step consumes
        const int p = k % DEPTH;            // compile-time after unroll
        const float m = (r >= 0 && r < IMG_H) ? 1.f : 0.f;

        // consume stage p -> masked diff
        float d[8];
        d[0] = (sxa[p].x - sya[p].x) * m; d[1] = (sxa[p].y - sya[p].y) * m;
        d[2] = (sxa[p].z - sya[p].z) * m; d[3] = (sxa[p].w - sya[p].w) * m;
        d[4] = (sxc[p].x - syc[p].x) * m; d[5] = (sxc[p].y - syc[p].y) * m;
        d[6] = (sxc[p].z - syc[p].z) * m; d[7] = (sxc[p].w - syc[p].w) * m;

        // refill stage p with row r+DEPTH (keeps 4 rows in flight)
        if (k + DEPTH < R + 4) issue(p, r + DEPTH);

        if (k < 4) {
            // warm-up: stash into ring slots 0..3, accumulate v
            #pragma unroll
            for (int j = 0; j < 8; ++j) { ring[k][j] = d[j]; v[j] += d[j]; }
        } else {
            const int i = i0 + (k - 4);     // output row (wave-uniform)
            const int slot = k % 5;         // compile-time after unroll
            #pragma unroll
            for (int j = 0; j < 8; ++j) {
                v[j] += d[j] - ring[slot][j];
                ring[slot][j] = d[j];
            }

            // halo: previous lane's v[4..7] = vsums for cols c0-4..c0-1
            float h0 = __shfl_up(v[4], 1, 64);
            float h1 = __shfl_up(v[5], 1, 64);
            float h2 = __shfl_up(v[6], 1, 64);
            float h3 = __shfl_up(v[7], 1, 64);
            if (lane == 0) { h0 = 0.f; h1 = 0.f; h2 = 0.f; h3 = 0.f; }

            // sliding horizontal 5-tap over {h0..h3, v0..v7}
            const float s0 = h0 + h1 + h2 + h3 + v[0];
            const float s1 = s0 + v[1] - h0;
            const float s2 = s1 + v[2] - h1;
            const float s3 = s2 + v[3] - h2;
            const float s4 = s3 + v[4] - h3;
            const float s5 = s4 + v[5] - v[0];
            const float s6 = s5 + v[6] - v[1];
            const float s7 = s6 + v[7] - v[2];

            const float rowmask = (i < OUT_H) ? 1.f : 0.f; // ragged last strip
            acc += rowmask * (fabsf(s0) + fabsf(s1) + fabsf(s2) + fabsf(s3)
                            + fabsf(s4) + fabsf(s5) + fabsf(s6) + fabsf(s7));

            // right edge: output cols 512..515 (truncated windows)
            const float em = (lane == 63) ? rowmask : 0.f;
            const float e0 = v[4] + v[5] + v[6] + v[7];
            const float e1 = v[5] + v[6] + v[7];
            const float e2 = v[6] + v[7];
            const float e3 = v[7];
            acc += em * (fabsf(e0) + fabsf(e1) + fabsf(e2) + fabsf(e3));
        }
    }

    // wave reduction, then one atomic per wave spread across 64 slots
    #pragma unroll
    for (int off = 32; off > 0; off >>= 1)
        acc += __shfl_down(acc, off, 64);
    if (lane == 0)
        atomicAdd(partial + (strip & (NPART - 1)), acc);
}

__global__ void finalize_kernel(const float* __restrict__ partial,
                                float* __restrict__ out)
{
    float s = 0.f;
    #pragma unroll
    for (int k = 0; k < NPART; ++k) s += partial[k];
    // each output scaled by 1/25 (uniform kernel), mean over 64*516*516
    out[0] = s * (1.0f / (25.0f * 64.0f * 516.0f * 516.0f));
}

extern "C" void kernel_launch(void* const* d_in, const int* in_sizes, int n_in,
                              void* d_out, int out_size, void* d_ws, size_t ws_size,
                              hipStream_t stream) {
    const float* x = (const float*)d_in[0];
    const float* y = (const float*)d_in[1];
    float* out = (float*)d_out;
    float* ws  = (float*)d_ws;

    hipMemsetAsync(ws, 0, NPART * sizeof(float), stream);

    dim3 grid(NBLK);   // 1040 blocks x 256 threads = 4160 waves
    box_loss_kernel<<<grid, NT, 0, stream>>>(x, y, ws);
    finalize_kernel<<<1, 1, 0, stream>>>(ws, out);
}

// Round 8
// 160.959 us; speedup vs baseline: 1.0761x; 1.0761x over previous
//
#include <hip/hip_runtime.h>

// mean(|box5(x) - box5(y)|), box5 = 5x5 uniform, pad=4.
// box(x)-box(y) = box(x-y), separable.
//
// One WAVE owns a 512-wide strip of R=8 output rows; lane owns 8 cols.
// Vertical 5-row rolling sum in registers (ring[5][8]); horizontal 5-tap
// via 4 x __shfl_up. No LDS, no barriers. (Same verified math as round 4.)
//
// Round-8 change: CHUNKED LOAD BURSTS. The 12 input rows are processed as
// 3 chunks of 4 rows. Each chunk's 16 float4 loads (8 KB contiguous of x,
// then 8 KB contiguous of y) are clustered between sched_barrier(0)
// fences so the scheduler must emit them back-to-back; waits stay
// compiler-managed (correct by construction — round 6/7's asm-register
// async loads were unsound and are abandoned).
// Theory: the 1.5-1.8 TB/s plateau is DRAM row-locality-limited — 2 KB
// bursts put ~2 lines per channel-row; 8 KB bursts put ~8, restoring
// copy-like streaming. launch_bounds(256,3) raises the scheduler's VGPR
// budget so 32 stage registers can stay live (round 1-5: its
// occupancy-targeted heuristic collapsed every deeper pipeline).

#define IMG_W 512
#define IMG_H 512
#define OUT_W 516
#define OUT_H 516
#define R     8                  // output rows per wave strip
#define SPI   65                 // ceil(516/8)
#define NT    256
#define WAVES (NT / 64)
#define NSTRIPS (64 * SPI)       // 4160 waves
#define NBLK  (NSTRIPS / WAVES)  // 1040 blocks (130 per XCD)
#define NPART 64

typedef float v4f __attribute__((ext_vector_type(4)));

// Load 4 consecutive (clamped) rows of x and y as two 8 KB contiguous
// bursts. Fences pin all 16 loads into one cluster.
__device__ __forceinline__ void load_chunk(
    const float* __restrict__ xb, const float* __restrict__ yb, int r0,
    v4f xa[4], v4f xc[4], v4f ya[4], v4f yc[4])
{
    __builtin_amdgcn_sched_barrier(0);
    #pragma unroll
    for (int mI = 0; mI < 4; ++mI) {
        const int rc = min(max(r0 + mI, 0), IMG_H - 1);
        const float* xr = xb + (size_t)rc * IMG_W;
        xa[mI] = *(const v4f*)(xr);
        xc[mI] = *(const v4f*)(xr + 4);
    }
    #pragma unroll
    for (int mI = 0; mI < 4; ++mI) {
        const int rc = min(max(r0 + mI, 0), IMG_H - 1);
        const float* yr = yb + (size_t)rc * IMG_W;
        ya[mI] = *(const v4f*)(yr);
        yc[mI] = *(const v4f*)(yr + 4);
    }
    __builtin_amdgcn_sched_barrier(0);
}

__global__ __launch_bounds__(NT, 3) void box_loss_kernel(
    const float* __restrict__ x, const float* __restrict__ y,
    float* __restrict__ partial)
{
    const int t    = threadIdx.x;
    const int lane = t & 63;
    const int wid  = t >> 6;

    // bijective XCD swizzle: 1040 blocks -> 130 contiguous per XCD
    const int bid  = blockIdx.x;
    const int swz  = (bid & 7) * (NBLK / 8) + (bid >> 3);

    const int strip = swz * WAVES + wid;            // 0..4159
    const int b  = strip / SPI;                     // batch image
    const int s  = strip - b * SPI;                 // strip in image
    const int i0 = s * R;                           // first output row
    const int c0 = lane * 8;                        // this lane's 8 columns

    const float* xb = x + (size_t)b * (IMG_W * IMG_H) + c0;
    const float* yb = y + (size_t)b * (IMG_W * IMG_H) + c0;

    // d-row history ring + vertical rolling sums, all in registers.
    float ring[5][8];
    float v[8];
    #pragma unroll
    for (int j = 0; j < 8; ++j) { v[j] = 0.f; ring[4][j] = 0.f; }

    float acc = 0.f;

    // 3 chunks of 4 input rows: chunk 0 = warm-up (rows i0-4..i0-1),
    // chunks 1,2 = rows i0..i0+7 -> output rows i0..i0+7.
    #pragma unroll
    for (int ch = 0; ch < 3; ++ch) {
        const int r0 = i0 - 4 + ch * 4;

        v4f xa[4], xc[4], ya[4], yc[4];
        load_chunk(xb, yb, r0, xa, xc, ya, yc);

        #pragma unroll
        for (int mI = 0; mI < 4; ++mI) {
            const int k = ch * 4 + mI;      // 0..11 (compile-time)
            const int r = r0 + mI;          // input row consumed
            const float m = (r >= 0 && r < IMG_H) ? 1.f : 0.f;

            float d[8];
            d[0] = (xa[mI].x - ya[mI].x) * m; d[1] = (xa[mI].y - ya[mI].y) * m;
            d[2] = (xa[mI].z - ya[mI].z) * m; d[3] = (xa[mI].w - ya[mI].w) * m;
            d[4] = (xc[mI].x - yc[mI].x) * m; d[5] = (xc[mI].y - yc[mI].y) * m;
            d[6] = (xc[mI].z - yc[mI].z) * m; d[7] = (xc[mI].w - yc[mI].w) * m;

            if (k < 4) {
                // warm-up: stash into ring slots 0..3, accumulate v
                #pragma unroll
                for (int j = 0; j < 8; ++j) { ring[k][j] = d[j]; v[j] += d[j]; }
            } else {
                const int i = i0 + (k - 4);     // output row (wave-uniform)
                const int slot = k % 5;         // compile-time after unroll
                #pragma unroll
                for (int j = 0; j < 8; ++j) {
                    v[j] += d[j] - ring[slot][j];
                    ring[slot][j] = d[j];
                }

                // halo: previous lane's v[4..7] = vsums for cols c0-4..c0-1
                float h0 = __shfl_up(v[4], 1, 64);
                float h1 = __shfl_up(v[5], 1, 64);
                float h2 = __shfl_up(v[6], 1, 64);
                float h3 = __shfl_up(v[7], 1, 64);
                if (lane == 0) { h0 = 0.f; h1 = 0.f; h2 = 0.f; h3 = 0.f; }

                // sliding horizontal 5-tap over {h0..h3, v0..v7}
                const float s0 = h0 + h1 + h2 + h3 + v[0];
                const float s1 = s0 + v[1] - h0;
                const float s2 = s1 + v[2] - h1;
                const float s3 = s2 + v[3] - h2;
                const float s4 = s3 + v[4] - h3;
                const float s5 = s4 + v[5] - v[0];
                const float s6 = s5 + v[6] - v[1];
                const float s7 = s6 + v[7] - v[2];

                const float rowmask = (i < OUT_H) ? 1.f : 0.f; // ragged strip
                acc += rowmask * (fabsf(s0) + fabsf(s1) + fabsf(s2) + fabsf(s3)
                                + fabsf(s4) + fabsf(s5) + fabsf(s6) + fabsf(s7));

                // right edge: output cols 512..515 (truncated windows)
                const float em = (lane == 63) ? rowmask : 0.f;
                const float e0 = v[4] + v[5] + v[6] + v[7];
                const float e1 = v[5] + v[6] + v[7];
                const float e2 = v[6] + v[7];
                const float e3 = v[7];
                acc += em * (fabsf(e0) + fabsf(e1) + fabsf(e2) + fabsf(e3));
            }
        }
    }

    // wave reduction, then one atomic per wave spread across 64 slots
    #pragma unroll
    for (int off = 32; off > 0; off >>= 1)
        acc += __shfl_down(acc, off, 64);
    if (lane == 0)
        atomicAdd(partial + (strip & (NPART - 1)), acc);
}

__global__ void finalize_kernel(const float* __restrict__ partial,
                                float* __restrict__ out)
{
    float s = 0.f;
    #pragma unroll
    for (int k = 0; k < NPART; ++k) s += partial[k];
    // each output scaled by 1/25 (uniform kernel), mean over 64*516*516
    out[0] = s * (1.0f / (25.0f * 64.0f * 516.0f * 516.0f));
}

extern "C" void kernel_launch(void* const* d_in, const int* in_sizes, int n_in,
                              void* d_out, int out_size, void* d_ws, size_t ws_size,
                              hipStream_t stream) {
    const float* x = (const float*)d_in[0];
    const float* y = (const float*)d_in[1];
    float* out = (float*)d_out;
    float* ws  = (float*)d_ws;

    hipMemsetAsync(ws, 0, NPART * sizeof(float), stream);

    dim3 grid(NBLK);   // 1040 blocks x 256 threads = 4160 waves
    box_loss_kernel<<<grid, NT, 0, stream>>>(x, y, ws);
    finalize_kernel<<<1, 1, 0, stream>>>(ws, out);
}

// Round 11
// 155.798 us; speedup vs baseline: 1.1118x; 1.0331x over previous
//
#include <hip/hip_runtime.h>

// mean(|box5(x) - box5(y)|), box5 = 5x5 uniform, pad=4.
// box(x)-box(y) = box(x-y), separable.
//
// One WAVE owns a 512-wide strip of R=8 output rows; lane owns 8 cols.
// Vertical 5-row rolling sum in registers (ring[5][8]); horizontal 5-tap
// via 4 x __shfl_up. No LDS, no barriers. (Same verified math as r4/r8.)
//
// Round-11: 2 CHUNKS OF 6 ROWS (12 KB bursts, 2 latency exposures/wave).
// Ladder: 2 KB/12 stalls = 68us (r4); 8 KB/3 stalls = 57us (r8).
// The 24 KB/1-stall endpoint (r9/r10 source) died twice to container
// failures — possibly compile/regalloc stress from the 48-load unroll —
// so this hedges: most of the ladder step at ~half the register pressure
// (~96 stage VGPRs vs ~192). Fences pin each chunk's 24 loads into one
// address-ordered cluster; waits stay compiler-managed (sound by
// construction). Pre-commit: if this ALSO fails infra, revert to the
// byte-identical r8 source next round.

#define IMG_W 512
#define IMG_H 512
#define OUT_W 516
#define OUT_H 516
#define R     8                  // output rows per wave strip
#define SPI   65                 // ceil(516/8)
#define NT    256
#define WAVES (NT / 64)
#define NSTRIPS (64 * SPI)       // 4160 waves
#define NBLK  (NSTRIPS / WAVES)  // 1040 blocks (130 per XCD)
#define NPART 64
#define CHROWS 6                 // rows per chunk (2 chunks = 12 rows)

typedef float v4f __attribute__((ext_vector_type(4)));

// Load 6 consecutive (clamped) rows of x and y as two 12 KB contiguous
// bursts. Fences pin all 24 loads into one issue cluster.
__device__ __forceinline__ void load_chunk6(
    const float* __restrict__ xb, const float* __restrict__ yb, int r0,
    v4f xa[CHROWS], v4f xc[CHROWS], v4f ya[CHROWS], v4f yc[CHROWS])
{
    __builtin_amdgcn_sched_barrier(0);
    #pragma unroll
    for (int mI = 0; mI < CHROWS; ++mI) {
        const int rc = min(max(r0 + mI, 0), IMG_H - 1);
        const float* xr = xb + (size_t)rc * IMG_W;
        xa[mI] = *(const v4f*)(xr);
        xc[mI] = *(const v4f*)(xr + 4);
    }
    #pragma unroll
    for (int mI = 0; mI < CHROWS; ++mI) {
        const int rc = min(max(r0 + mI, 0), IMG_H - 1);
        const float* yr = yb + (size_t)rc * IMG_W;
        ya[mI] = *(const v4f*)(yr);
        yc[mI] = *(const v4f*)(yr + 4);
    }
    __builtin_amdgcn_sched_barrier(0);
}

__global__ __launch_bounds__(NT, 2) void box_loss_kernel(
    const float* __restrict__ x, const float* __restrict__ y,
    float* __restrict__ partial)
{
    const int t    = threadIdx.x;
    const int lane = t & 63;
    const int wid  = t >> 6;

    // bijective XCD swizzle: 1040 blocks -> 130 contiguous per XCD
    const int bid  = blockIdx.x;
    const int swz  = (bid & 7) * (NBLK / 8) + (bid >> 3);

    const int strip = swz * WAVES + wid;            // 0..4159
    const int b  = strip / SPI;                     // batch image
    const int s  = strip - b * SPI;                 // strip in image
    const int i0 = s * R;                           // first output row
    const int c0 = lane * 8;                        // this lane's 8 columns

    const float* xb = x + (size_t)b * (IMG_W * IMG_H) + c0;
    const float* yb = y + (size_t)b * (IMG_W * IMG_H) + c0;

    // d-row history ring + vertical rolling sums, all in registers.
    float ring[5][8];
    float v[8];
    #pragma unroll
    for (int j = 0; j < 8; ++j) { v[j] = 0.f; ring[4][j] = 0.f; }

    float acc = 0.f;

    // 2 chunks of 6 input rows: rows i0-4 .. i0+7.
    // k=0..3 warm-up, k=4..11 -> output rows i0..i0+7.
    #pragma unroll
    for (int ch = 0; ch < 2; ++ch) {
        const int r0 = i0 - 4 + ch * CHROWS;

        v4f xa[CHROWS], xc[CHROWS], ya[CHROWS], yc[CHROWS];
        load_chunk6(xb, yb, r0, xa, xc, ya, yc);

        #pragma unroll
        for (int mI = 0; mI < CHROWS; ++mI) {
            const int k = ch * CHROWS + mI; // 0..11 (compile-time)
            const int r = r0 + mI;          // input row consumed
            const float m = (r >= 0 && r < IMG_H) ? 1.f : 0.f;

            float d[8];
            d[0] = (xa[mI].x - ya[mI].x) * m; d[1] = (xa[mI].y - ya[mI].y) * m;
            d[2] = (xa[mI].z - ya[mI].z) * m; d[3] = (xa[mI].w - ya[mI].w) * m;
            d[4] = (xc[mI].x - yc[mI].x) * m; d[5] = (xc[mI].y - yc[mI].y) * m;
            d[6] = (xc[mI].z - yc[mI].z) * m; d[7] = (xc[mI].w - yc[mI].w) * m;

            if (k < 4) {
                // warm-up: stash into ring slots 0..3, accumulate v
                #pragma unroll
                for (int j = 0; j < 8; ++j) { ring[k][j] = d[j]; v[j] += d[j]; }
            } else {
                const int i = i0 + (k - 4);     // output row (wave-uniform)
                const int slot = k % 5;         // compile-time after unroll
                #pragma unroll
                for (int j = 0; j < 8; ++j) {
                    v[j] += d[j] - ring[slot][j];
                    ring[slot][j] = d[j];
                }

                // halo: previous lane's v[4..7] = vsums for cols c0-4..c0-1
                float h0 = __shfl_up(v[4], 1, 64);
                float h1 = __shfl_up(v[5], 1, 64);
                float h2 = __shfl_up(v[6], 1, 64);
                float h3 = __shfl_up(v[7], 1, 64);
                if (lane == 0) { h0 = 0.f; h1 = 0.f; h2 = 0.f; h3 = 0.f; }

                // sliding horizontal 5-tap over {h0..h3, v0..v7}
                const float s0 = h0 + h1 + h2 + h3 + v[0];
                const float s1 = s0 + v[1] - h0;
                const float s2 = s1 + v[2] - h1;
                const float s3 = s2 + v[3] - h2;
                const float s4 = s3 + v[4] - h3;
                const float s5 = s4 + v[5] - v[0];
                const float s6 = s5 + v[6] - v[1];
                const float s7 = s6 + v[7] - v[2];

                const float rowmask = (i < OUT_H) ? 1.f : 0.f; // ragged strip
                acc += rowmask * (fabsf(s0) + fabsf(s1) + fabsf(s2) + fabsf(s3)
                                + fabsf(s4) + fabsf(s5) + fabsf(s6) + fabsf(s7));

                // right edge: output cols 512..515 (truncated windows)
                const float em = (lane == 63) ? rowmask : 0.f;
                const float e0 = v[4] + v[5] + v[6] + v[7];
                const float e1 = v[5] + v[6] + v[7];
                const float e2 = v[6] + v[7];
                const float e3 = v[7];
                acc += em * (fabsf(e0) + fabsf(e1) + fabsf(e2) + fabsf(e3));
            }
        }
    }

    // wave reduction, then one atomic per wave spread across 64 slots
    #pragma unroll
    for (int off = 32; off > 0; off >>= 1)
        acc += __shfl_down(acc, off, 64);
    if (lane == 0)
        atomicAdd(partial + (strip & (NPART - 1)), acc);
}

__global__ void finalize_kernel(const float* __restrict__ partial,
                                float* __restrict__ out)
{
    float s = 0.f;
    #pragma unroll
    for (int k = 0; k < NPART; ++k) s += partial[k];
    // each output scaled by 1/25 (uniform kernel), mean over 64*516*516
    out[0] = s * (1.0f / (25.0f * 64.0f * 516.0f * 516.0f));
}

extern "C" void kernel_launch(void* const* d_in, const int* in_sizes, int n_in,
                              void* d_out, int out_size, void* d_ws, size_t ws_size,
                              hipStream_t stream) {
    const float* x = (const float*)d_in[0];
    const float* y = (const float*)d_in[1];
    float* out = (float*)d_out;
    float* ws  = (float*)d_ws;

    hipMemsetAsync(ws, 0, NPART * sizeof(float), stream);

    dim3 grid(NBLK);   // 1040 blocks x 256 threads = 4160 waves
    box_loss_kernel<<<grid, NT, 0, stream>>>(x, y, ws);
    finalize_kernel<<<1, 1, 0, stream>>>(ws, out);
}